// Round 1
// baseline (231.566 us; speedup 1.0000x reference)
//
#include <hip/hip_runtime.h>

#define T_STEPS 1000
#define B_ROWS 65536
#define N_FCAT 24
#define N_DCAT 298
#define NUM_NUM 16
#define MO_STRIDE 314

__constant__ int c_numc[N_FCAT] = {2,2,3,4,5,6,8,10,10,12,16,16,20,24,32,40,2,3,4,5,6,8,10,50};
__constant__ int c_off[N_FCAT]  = {0,2,4,7,11,16,22,30,40,50,62,78,94,114,138,170,210,212,215,219,224,230,238,248};

// ws layout (floats): [0,1000) LOG_ALPHA | [1000,2000) LOG_1M_ALPHA |
//                     [2000,3000) LOG_CA | [3000,4000) LOG_1M_CA | [4000,4024) LOG_K
__global__ void build_tables_kernel(float* __restrict__ ws) {
  __shared__ double sh[1024];
  int i = threadIdx.x;
  double la = 0.0;
  if (i < T_STEPS) {
    const double PI = 3.14159265358979323846;
    double u0 = (double)i / (double)T_STEPS;
    double u1 = (double)(i + 1) / (double)T_STEPS;
    double c0 = cos((u0 + 0.008) / 1.008 * PI * 0.5);
    double c1 = cos((u1 + 0.008) / 1.008 * PI * 0.5);
    double ab0 = c0 * c0, ab1 = c1 * c1;
    double beta = 1.0 - ab1 / ab0;
    if (beta > 0.2) beta = 0.2;
    la = log(1.0 - beta);
  }
  sh[i] = la;
  __syncthreads();
  // inclusive Hillis-Steele scan (double) for cumsum(log_alpha)
  double run = la;
  for (int ofs = 1; ofs < 1024; ofs <<= 1) {
    double add = (i >= ofs) ? sh[i - ofs] : 0.0;
    __syncthreads();
    run += add;
    sh[i] = run;
    __syncthreads();
  }
  if (i < T_STEPS) {
    ws[i]               = (float)la;
    ws[T_STEPS + i]     = (float)log(-expm1(la));
    ws[2 * T_STEPS + i] = (float)run;
    ws[3 * T_STEPS + i] = (float)log(-expm1(run));
  }
  if (i < N_FCAT) ws[4 * T_STEPS + i] = (float)log((double)c_numc[i]);
}

__device__ __forceinline__ float lae(float a, float b) {
  float m = fmaxf(a, b);
  return m + logf(expf(a - m) + expf(b - m));
}

#define NEGL -69.07755278982137f   // log(float32(1e-30))
#define NINF -1e38f

__global__ __launch_bounds__(256) void gmd_kernel(
    const int* __restrict__ xci, const int* __restrict__ tarr,
    const float* __restrict__ noise, const float* __restrict__ ucat,
    const float* __restrict__ mo, const float* __restrict__ ws,
    float* __restrict__ out)
{
  int tid = blockIdx.x * blockDim.x + threadIdx.x;
  int row = tid >> 2;   // 4 threads per row
  int g   = tid & 3;
  if (row >= B_ROWS) return;

  const float* LA   = ws;
  const float* L1A  = ws + T_STEPS;
  const float* LCA  = ws + 2 * T_STEPS;
  const float* L1CA = ws + 3 * T_STEPS;
  const float* LK   = ws + 4 * T_STEPS;

  int t = tarr[row];
  bool t0 = (t == 0);
  int tm1 = t0 ? 0 : t - 1;
  float la_t  = LA[t],    l1a_t  = L1A[t];
  float lca_t = LCA[t],   l1ca_t = L1CA[t];
  float lca_p = LCA[tm1], l1ca_p = L1CA[tm1];
  float lca_T = LCA[T_STEPS - 1], l1ca_T = L1CA[T_STEPS - 1];

  const float* morow = mo + (size_t)row * MO_STRIDE;
  const float* mocat = morow + NUM_NUM;
  const float* urow  = ucat + (size_t)row * N_DCAT;

  // Gaussian part: 4 of 16 elements per lane
  float gauss = 0.f;
  #pragma unroll
  for (int i = 0; i < 4; ++i) {
    int c = g * 4 + i;
    float d = noise[row * NUM_NUM + c] - morow[c];
    gauss = fmaf(d, d, gauss);
  }

  float multi = 0.f;

  for (int f = 0; f < N_FCAT; ++f) {
    int K = c_numc[f];
    int off = c_off[f];
    float logK = LK[f];
    int h = xci[row * N_FCAT + f];

    // per-feature constants (identical across the quad -> free in wave time)
    float cb_t = l1ca_t - logK;
    float ev_h = lae(lca_t, cb_t);          // q_pred at hot
    float ev_n = lae(NEGL + lca_t, cb_t);   // q_pred at non-hot

    // ---- pass 1: online lse(model_out_cat) + gumbel-score argmax ----
    float m1 = NINF, s1 = 0.f;
    float smax = NINF; int jm = 0x7fffffff;
    for (int j = g; j < K; j += 4) {
      float x = mocat[off + j];
      float nm = fmaxf(m1, x);
      s1 = s1 * expf(m1 - nm) + expf(x - nm);
      m1 = nm;
      float u = urow[off + j];
      u = fminf(fmaxf(u, 1e-30f), 1.0f);
      float gum = -logf(-logf(u));
      float sc = ((j == h) ? ev_h : ev_n) + gum;
      if (sc > smax) { smax = sc; jm = j; }
    }
    // quad all-reduce: (m1,s1) lse-merge and (smax,jm) argmax
    #pragma unroll
    for (int d = 1; d < 4; d <<= 1) {
      float om = __shfl_xor(m1, d);
      float os = __shfl_xor(s1, d);
      float nm = fmaxf(m1, om);
      s1 = s1 * expf(m1 - nm) + os * expf(om - nm);
      m1 = nm;
      float osx = __shfl_xor(smax, d);
      int   oj  = __shfl_xor(jm, d);
      if (osx > smax || (osx == smax && oj < jm)) { smax = osx; jm = oj; }
    }
    float lse1 = m1 + logf(s1);

    float cb_1 = l1a_t - logK;
    float q1h = lae(la_t, cb_1);          // q_pred_one_timestep at sampled pos
    float q1n = lae(NEGL + la_t, cb_1);
    float cb_p = l1ca_p - logK;
    float levt_h = t0 ? 0.f  : lae(lca_p, cb_p);        // true-posterior lev
    float levt_n = t0 ? NEGL : lae(NEGL + lca_p, cb_p);

    // ---- pass 2: un_model / un_true online accumulations ----
    float mm = NINF, Sm = 0.f;             // lse of un_model
    float mt = NINF, St = 0.f, Wt = 0.f;   // lse of un_true + sum e^{un_t}(un_t-un_m)
    float unh = 0.f;                       // un_model at hot index
    for (int j = g; j < K; j += 4) {
      float lr = mocat[off + j] - lse1;    // log_x0_recon
      float lev_m = t0 ? lr : lae(lr + lca_p, cb_p);
      float q1 = (j == jm) ? q1h : q1n;
      float un_m = lev_m + q1;
      float un_t = ((j == h) ? levt_h : levt_n) + q1;
      float nm = fmaxf(mm, un_m);
      Sm = Sm * expf(mm - nm) + expf(un_m - nm);
      mm = nm;
      float nt = fmaxf(mt, un_t);
      float sc2 = expf(mt - nt), e2 = expf(un_t - nt);
      St = St * sc2 + e2;
      Wt = Wt * sc2 + e2 * (un_t - un_m);
      mt = nt;
      if (j == h) unh = un_m;
    }
    #pragma unroll
    for (int d = 1; d < 4; d <<= 1) {
      float om = __shfl_xor(mm, d), os = __shfl_xor(Sm, d);
      float nm = fmaxf(mm, om);
      Sm = Sm * expf(mm - nm) + os * expf(om - nm);
      mm = nm;
      float omt = __shfl_xor(mt, d), ost = __shfl_xor(St, d), owt = __shfl_xor(Wt, d);
      float nt = fmaxf(mt, omt);
      float sa = expf(mt - nt), sb = expf(omt - nt);
      St = St * sa + ost * sb;
      Wt = Wt * sa + owt * sb;
      mt = nt;
      unh += __shfl_xor(unh, d);
    }
    float lse_m = mm + logf(Sm);
    float lse_t = mt + logf(St);
    float kl  = Wt / St - lse_t + lse_m;
    float dec = lse_m - unh;               // decoder_nll (1e-30 tail negligible)
    float ltf = t0 ? dec : kl;

    // kl_prior: closed form (qxT takes 2 values per feature)
    float cb_T = l1ca_T - logK;
    float qh = lae(lca_T, cb_T);
    float qn = lae(NEGL + lca_T, cb_T);
    float klp = expf(qh) * (qh + logK) + (float)(K - 1) * (expf(qn) * (qn + logK));

    multi += ltf * 1000.0f + klp;
  }

  // multi is identical on all 4 lanes (all-reduced per feature); gauss is not
  gauss += __shfl_xor(gauss, 1);
  gauss += __shfl_xor(gauss, 2);
  if (g == 0) out[row] = multi / 24.0f + gauss / 16.0f;
}

extern "C" void kernel_launch(void* const* d_in, const int* in_sizes, int n_in,
                              void* d_out, int out_size, void* d_ws, size_t ws_size,
                              hipStream_t stream) {
  const int*   xci   = (const int*)d_in[0];
  const int*   tarr  = (const int*)d_in[1];
  const float* noise = (const float*)d_in[2];
  const float* ucat  = (const float*)d_in[3];
  const float* mo    = (const float*)d_in[4];
  float* out = (float*)d_out;
  float* ws  = (float*)d_ws;

  hipLaunchKernelGGL(build_tables_kernel, dim3(1), dim3(1024), 0, stream, ws);
  hipLaunchKernelGGL(gmd_kernel, dim3((B_ROWS * 4) / 256), dim3(256), 0, stream,
                     xci, tarr, noise, ucat, mo, ws, out);
}

// Round 2
// 140.508 us; speedup vs baseline: 1.6481x; 1.6481x over previous
//
#include <hip/hip_runtime.h>
#include <math.h>

#define T_STEPS 1000
#define B_ROWS 65536
#define N_FCAT 24
#define N_DCAT 298
#define NUM_NUM 16
#define MO_STRIDE 314
#define NKID 14
#define NEGL -69.07755278982137f   // log(float32(1e-30))
#define NINF -1e38f

__constant__ int c_numc[N_FCAT] = {2,2,3,4,5,6,8,10,10,12,16,16,20,24,32,40,2,3,4,5,6,8,10,50};
__constant__ int c_off[N_FCAT]  = {0,2,4,7,11,16,22,30,40,50,62,78,94,114,138,170,210,212,215,219,224,230,238,248};
__constant__ int c_kid[N_FCAT]  = {0,0,1,2,3,4,5,6,6,7,8,8,9,10,11,12,0,1,2,3,4,5,6,13};
__constant__ int c_kval[NKID]   = {2,3,4,5,6,8,10,12,16,20,24,32,40,50};

// persistent module-owned tables, rebuilt deterministically every launch
__device__ float  g_sched[4*T_STEPS];      // LA | L1A | LCA | L1CA
__device__ float  g_ecap[T_STEPS];         // exp(LCA[t-1]) (1.0 at t=0)
__device__ float4 g_tab4[T_STEPS*NKID*3];  // per (t,kidx): 12 floats
__device__ float  g_klp;                   // sum over features of kl_prior

__device__ __forceinline__ float lae(float a, float b) {   // precise f32 (argmax path)
  float m = fmaxf(a, b);
  return m + logf(expf(a - m) + expf(b - m));
}
__device__ __forceinline__ double lad(double a, double b) {
  double m = fmax(a, b);
  return m + log(exp(a - m) + exp(b - m));
}

__global__ void build_sched_kernel() {
  __shared__ double sh[1024];
  int i = threadIdx.x;
  double la = 0.0;
  if (i < T_STEPS) {
    const double PI = 3.14159265358979323846;
    double u0 = (double)i / 1000.0, u1 = (double)(i + 1) / 1000.0;
    double c0 = cos((u0 + 0.008) / 1.008 * PI * 0.5);
    double c1 = cos((u1 + 0.008) / 1.008 * PI * 0.5);
    double beta = 1.0 - (c1 * c1) / (c0 * c0);
    if (beta > 0.2) beta = 0.2;
    la = log(1.0 - beta);
  }
  sh[i] = la;
  __syncthreads();
  double run = la;
  for (int ofs = 1; ofs < 1024; ofs <<= 1) {
    double add = (i >= ofs) ? sh[i - ofs] : 0.0;
    __syncthreads();
    run += add;
    sh[i] = run;
    __syncthreads();
  }
  if (i < T_STEPS) {
    g_sched[i]               = (float)la;
    g_sched[T_STEPS + i]     = (float)log(-expm1(la));
    g_sched[2 * T_STEPS + i] = (float)run;
    g_sched[3 * T_STEPS + i] = (float)log(-expm1(run));
  }
}

__global__ void build_tab_kernel() {
  int e = blockIdx.x * blockDim.x + threadIdx.x;
  if (e < T_STEPS * NKID) {
    int t = e / NKID, k = e - t * NKID;
    bool t0 = (t == 0);
    int tm1 = t0 ? 0 : t - 1;
    float la = g_sched[t], l1a = g_sched[T_STEPS + t];
    float lca = g_sched[2 * T_STEPS + t], l1ca = g_sched[3 * T_STEPS + t];
    float lca_p = g_sched[2 * T_STEPS + tm1], l1ca_p = g_sched[3 * T_STEPS + tm1];
    float logK = (float)log((double)c_kval[k]);
    // ---- argmax-critical: identical f32 sequence to the verified round-1 kernel ----
    float cb_t = l1ca - logK;
    float ev_h = lae(lca, cb_t);
    float ev_n = lae(NEGL + lca, cb_t);
    // ---- value path: double precision ----
    double cb1 = (double)l1a - (double)logK;
    double q1h = lad((double)la, cb1);
    double q1n = lad((double)NEGL + (double)la, cb1);
    double cbp = (double)l1ca_p - (double)logK;
    double levth = t0 ? 0.0 : lad((double)lca_p, cbp);
    double levtn = t0 ? (double)NEGL : lad((double)NEGL + (double)lca_p, cbp);
    float4* o = g_tab4 + e * 3;
    o[0] = make_float4(ev_h, ev_n, (float)q1h, (float)q1n);
    o[1] = make_float4((float)exp(q1h), (float)exp(q1n), (float)exp(levth), (float)exp(levtn));
    o[2] = make_float4((float)levth, (float)levtn, t0 ? 0.f : (float)exp(cbp), 0.f);
    if (k == 0) g_ecap[t] = t0 ? 1.f : (float)exp((double)lca_p);
  }
  if (e == 0) {
    double lcaT = g_sched[2 * T_STEPS + T_STEPS - 1];
    double l1caT = g_sched[3 * T_STEPS + T_STEPS - 1];
    double s = 0.0;
    for (int f = 0; f < N_FCAT; ++f) {
      double logK = log((double)c_numc[f]);
      double cbT = l1caT - logK;
      double qh = lad(lcaT, cbT);
      double qn = lad((double)NEGL + lcaT, cbT);
      s += exp(qh) * (qh + logK) + (double)(c_numc[f] - 1) * exp(qn) * (qn + logK);
    }
    g_klp = (float)s;
  }
}

// ---- quad (4-lane) reductions via DPP quad_perm: xor1=0xB1, xor2=0x4E ----
__device__ __forceinline__ float qsum(float v) {
  v += __int_as_float(__builtin_amdgcn_mov_dpp(__float_as_int(v), 0xB1, 0xF, 0xF, true));
  v += __int_as_float(__builtin_amdgcn_mov_dpp(__float_as_int(v), 0x4E, 0xF, 0xF, true));
  return v;
}
__device__ __forceinline__ void qargmax(float& smax, int& jm) {
  float os = __int_as_float(__builtin_amdgcn_mov_dpp(__float_as_int(smax), 0xB1, 0xF, 0xF, true));
  int   oj = __builtin_amdgcn_mov_dpp(jm, 0xB1, 0xF, 0xF, true);
  if (os > smax || (os == smax && oj < jm)) { smax = os; jm = oj; }
  os = __int_as_float(__builtin_amdgcn_mov_dpp(__float_as_int(smax), 0x4E, 0xF, 0xF, true));
  oj = __builtin_amdgcn_mov_dpp(jm, 0x4E, 0xF, 0xF, true);
  if (os > smax || (os == smax && oj < jm)) { smax = os; jm = oj; }
}

__global__ __launch_bounds__(256) void gmd_kernel(
    const int* __restrict__ xci, const int* __restrict__ tarr,
    const float* __restrict__ noise, const float* __restrict__ ucat,
    const float* __restrict__ mo, float* __restrict__ out)
{
  int tid = blockIdx.x * blockDim.x + threadIdx.x;
  int row = tid >> 2;   // 4 threads per row
  int g   = tid & 3;
  if (row >= B_ROWS) return;

  int t = tarr[row];
  bool t0 = (t == 0);
  float ecap = g_ecap[t];

  const float* morow = mo + (size_t)row * MO_STRIDE;
  const float* mocat = morow + NUM_NUM;
  const float* urow  = ucat + (size_t)row * N_DCAT;

  float gauss = 0.f;
  #pragma unroll
  for (int i = 0; i < 4; ++i) {
    int c = g * 4 + i;
    float d = noise[row * NUM_NUM + c] - morow[c];
    gauss = fmaf(d, d, gauss);
  }

  float multi = 0.f;

  for (int f = 0; f < N_FCAT; ++f) {
    int K = c_numc[f];
    int off = c_off[f];
    int h = xci[row * N_FCAT + f];
    const float4* tb = g_tab4 + ((size_t)t * NKID + c_kid[f]) * 3;
    float4 ta = tb[0], tbv = tb[1], tc = tb[2];
    float ev_h = ta.x, ev_n = ta.y, q1h = ta.z, q1n = ta.w;
    float q1he = tbv.x, q1ne = tbv.y, eth = tbv.z, etn = tbv.w;
    float levth = tc.x, levtn = tc.y, cbpe = tc.z;

    // ---- pass 1: sum exp(model_out) + gumbel-score argmax (score path = round-1 exact) ----
    float s1 = 0.f, smax = NINF;
    int jm = 0x7fffffff;
    for (int j = g; j < K; j += 4) {
      float x = mocat[off + j];
      s1 += __expf(x);
      float u = urow[off + j];
      u = fminf(fmaxf(u, 1e-30f), 1.0f);
      float gum = -logf(-logf(u));
      float sc = ((j == h) ? ev_h : ev_n) + gum;
      if (sc > smax) { smax = sc; jm = j; }
    }
    s1 = qsum(s1);
    qargmax(smax, jm);

    float ca = ecap / s1;   // exp(lca_{t-1}) / sum(exp(mocat))   (t=0: 1/s1)

    // ---- pass 2: E_j = exp(lev_m_j);  direct linear-space accumulation ----
    float Sm = 0.f, Bv = 0.f, lmh = 0.f;
    for (int j = g; j < K; j += 4) {
      float x = mocat[off + j];
      float E = fmaf(__expf(x), ca, cbpe);     // e^{lr+lca_p} + e^{cb_p}
      float lm = __logf(E);                    // lev_m_j
      float qe = (j == jm) ? q1he : q1ne;      // e^{q1_j}
      Sm = fmaf(E, qe, Sm);                    // sum e^{un_m}
      float c = ((j == h) ? eth : etn) * qe;   // e^{un_t_j}
      Bv = fmaf(c, lm, Bv);                    // sum e^{un_t} * lev_m
      lmh += (j == h) ? lm : 0.f;
    }
    Sm = qsum(Sm); Bv = qsum(Bv); lmh = qsum(lmh);

    float lse_m = __logf(Sm);
    bool hm = (h == jm);
    float Kf2 = (float)K - 2.f + (hm ? 1.f : 0.f);
    float coefH = eth * (hm ? q1he : q1ne);
    float coefJ = hm ? 0.f : etn * q1he;
    float cn = etn * q1ne;
    float A  = cn * levtn * Kf2 + coefH * levth + coefJ * levtn;  // sum e^{un_t} * levt
    float St = cn * Kf2 + coefH + coefJ;                          // sum e^{un_t}
    float kl = (A - Bv) / St - __logf(St) + lse_m;
    float unh = lmh + (hm ? q1h : q1n);
    float dec = lse_m - unh;
    multi += t0 ? dec : kl;
  }

  gauss = qsum(gauss);
  if (g == 0) out[row] = (multi * 1000.f + g_klp) / 24.f + gauss / 16.f;
}

extern "C" void kernel_launch(void* const* d_in, const int* in_sizes, int n_in,
                              void* d_out, int out_size, void* d_ws, size_t ws_size,
                              hipStream_t stream) {
  const int*   xci   = (const int*)d_in[0];
  const int*   tarr  = (const int*)d_in[1];
  const float* noise = (const float*)d_in[2];
  const float* ucat  = (const float*)d_in[3];
  const float* mo    = (const float*)d_in[4];
  float* out = (float*)d_out;
  (void)d_ws; (void)ws_size;

  hipLaunchKernelGGL(build_sched_kernel, dim3(1), dim3(1024), 0, stream);
  hipLaunchKernelGGL(build_tab_kernel, dim3((T_STEPS * NKID + 255) / 256), dim3(256), 0, stream);
  hipLaunchKernelGGL(gmd_kernel, dim3((B_ROWS * 4) / 256), dim3(256), 0, stream,
                     xci, tarr, noise, ucat, mo, out);
}